// Round 9
// baseline (209.896 us; speedup 1.0000x reference)
//
#include <hip/hip_runtime.h>

#define HID 64
#define DIN 128
#define NBLK 512                // blocks for the build pass
#define CSH 14                  // slab capacity shift: 16384 entries per bucket
#define CAP (1 << CSH)
#define PAD 68                  // float4-aligned LDS row stride

typedef unsigned long long ull;
typedef unsigned short u16;

static __device__ __forceinline__ u16 f2bf(float f) {
  unsigned u = __float_as_uint(f);
  unsigned lsb = (u >> 16) & 1u;
  u += 0x7fffu + lsb;
  return (u16)(u >> 16);
}

// ============ shared gemm tile: NT threads, (NT/8)x64 output, self-transposing W ====
// out[n0+m][j] = sum_d X[n0+m][d] * W[j][d];  m = ty, ty+NT/16; j = 4*tx..4*tx+3.
// W staging lane map: qd wave-uniform, j lane-sweep -> each transpose write hits 64
// consecutive floats of one LDS row = 2 lanes/bank, conflict-free (round-7 fix:
// 1.65M -> 100K SQ_LDS_BANK_CONFLICT). XT_PRELOADED: XT filled by caller.

template <int K, int NT, bool XT_PRELOADED>
__device__ __forceinline__ void gemm_tile(const float* __restrict__ X,
                                          const float* __restrict__ W,
                                          u16* __restrict__ out,
                                          float* XT, float* WL,
                                          int n0, int n_nodes, int tid) {
  constexpr int ROWS = NT / 8;            // 64 (NT=512) or 32 (NT=256)
  const int tx = tid & 15;
  const int ty = tid >> 4;                // 0..NT/16-1
  float acc[2][4] = {{0.f}};

  for (int ph = 0; ph < K / 64; ++ph) {
    const int d0 = ph * 64;
    __syncthreads();
    if (!XT_PRELOADED) {
#pragma unroll
      for (int k = 0; k < 2; ++k) {       // ROWS*16 slots = NT*2
        int f = tid + k * NT;
        int r = f >> 4, q = f & 15;
        int n = n0 + r;
        float4 xv = (n < n_nodes)
          ? *reinterpret_cast<const float4*>(&X[(size_t)n * K + d0 + 4 * q])
          : make_float4(0.f, 0.f, 0.f, 0.f);
        *reinterpret_cast<float4*>(&XT[r * PAD + 4 * q]) = xv;
      }
    }
#pragma unroll
    for (int k = 0; k < 1024 / NT; ++k) { // 1024 slots: 16 d-quads x 64 j
      int gq = tid + k * NT;
      int qd = gq >> 6, j = gq & 63;
      float4 wv = *reinterpret_cast<const float4*>(&W[(size_t)j * K + d0 + 4 * qd]);
      WL[(4 * qd + 0) * PAD + j] = wv.x;
      WL[(4 * qd + 1) * PAD + j] = wv.y;
      WL[(4 * qd + 2) * PAD + j] = wv.z;
      WL[(4 * qd + 3) * PAD + j] = wv.w;
    }
    __syncthreads();
#pragma unroll 4
    for (int dd = 0; dd < 64; dd += 4) {
      float4 ws[4];
#pragma unroll
      for (int dk = 0; dk < 4; ++dk)
        ws[dk] = *reinterpret_cast<const float4*>(&WL[(dd + dk) * PAD + 4 * tx]);
      float4 x0 = *reinterpret_cast<const float4*>(&XT[ty * PAD + dd]);
      float4 x1 = *reinterpret_cast<const float4*>(&XT[(ty + ROWS / 2) * PAD + dd]);
      float xm0[4] = {x0.x, x0.y, x0.z, x0.w};
      float xm1[4] = {x1.x, x1.y, x1.z, x1.w};
#pragma unroll
      for (int dk = 0; dk < 4; ++dk) {
        acc[0][0] = fmaf(xm0[dk], ws[dk].x, acc[0][0]);
        acc[0][1] = fmaf(xm0[dk], ws[dk].y, acc[0][1]);
        acc[0][2] = fmaf(xm0[dk], ws[dk].z, acc[0][2]);
        acc[0][3] = fmaf(xm0[dk], ws[dk].w, acc[0][3]);
        acc[1][0] = fmaf(xm1[dk], ws[dk].x, acc[1][0]);
        acc[1][1] = fmaf(xm1[dk], ws[dk].y, acc[1][1]);
        acc[1][2] = fmaf(xm1[dk], ws[dk].z, acc[1][2]);
        acc[1][3] = fmaf(xm1[dk], ws[dk].w, acc[1][3]);
      }
    }
  }

#pragma unroll
  for (int mi = 0; mi < 2; ++mi) {
    int n = n0 + mi * (ROWS / 2) + ty;
    if (n < n_nodes) {
      ushort4 o = make_ushort4(f2bf(acc[mi][0]), f2bf(acc[mi][1]),
                               f2bf(acc[mi][2]), f2bf(acc[mi][3]));
      *reinterpret_cast<ushort4*>(&out[(size_t)n * HID + 4 * tx]) = o;
    }
  }
}

// ============ K1: fused build + layer-1 GEMM (independent block roles) ============
// b < NBLK: edge build. Round-9 form: edges REGISTER-CACHED across both passes
// (loaded once; hist and scatter run from registers), and histogram/cursors are
// SPLIT PER HALF-BLOCK (h0/h1, cur0/cur1) to halve LDS-atomic contention; half 1's
// reserved run starts at ofs+c0. Per-edge atomics LDS-only (round-3 lesson:
// per-edge GLOBAL atomics = 100MB writeback, never). b >= NBLK: 64x64 gemm1 tile.

__global__ __launch_bounds__(512) void k_build_gemm(const int* __restrict__ src,
                                                    const int* __restrict__ dst,
                                                    const float* __restrict__ ew,
                                                    int* __restrict__ cursor,
                                                    int2* __restrict__ bufA,
                                                    int E, int chunk,
                                                    const float* __restrict__ x,
                                                    const float* __restrict__ W1,
                                                    u16* __restrict__ h,
                                                    int n_nodes) {
  __shared__ float S[2 * 64 * PAD];
  int b = blockIdx.x, tid = threadIdx.x;
  if (b >= NBLK) {               // gemm1 tile blocks
    gemm_tile<DIN, 512, false>(x, W1, h, S, S + 64 * PAD, (b - NBLK) * 64, n_nodes, tid);
    return;
  }
  int* h0   = (int*)S;           // half-0 histogram
  int* h1_  = (int*)S + 256;     // half-1 histogram
  int* cur0 = (int*)S + 512;     // half-0 scatter cursors
  int* cur1 = (int*)S + 768;     // half-1 scatter cursors
  if (tid < 256) { h0[tid] = 0; h1_[tid] = 0; }
  __syncthreads();
  int e0 = b * chunk, e1 = min(E, e0 + chunk);   // chunk%4==0 and E%4==0 -> (e1-e0)%4==0
  const int half = tid >> 8;
  int* hh = half ? h1_ : h0;
  // pass 1: load edges ONCE into registers (<=2 groups of 4), histogram from regs
  int4 s4[2], d4[2];
  float4 w4[2];
  bool val[2];
#pragma unroll
  for (int it = 0; it < 2; ++it) {
    int e = e0 + 4 * tid + it * 2048;
    val[it] = (e < e1);
    if (val[it]) {
      s4[it] = *reinterpret_cast<const int4*>(&src[e]);
      d4[it] = *reinterpret_cast<const int4*>(&dst[e]);
      w4[it] = *reinterpret_cast<const float4*>(&ew[e]);
      atomicAdd(&hh[d4[it].x >> 8], 1);
      atomicAdd(&hh[d4[it].y >> 8], 1);
      atomicAdd(&hh[d4[it].z >> 8], 1);
      atomicAdd(&hh[d4[it].w >> 8], 1);
    }
  }
  // residual (chunk > 4096; dead for E=1.6M): histogram uncached
  for (int e = e0 + 4096 + 4 * tid; e < e1; e += 2048) {
    int4 dd = *reinterpret_cast<const int4*>(&dst[e]);
    atomicAdd(&hh[dd.x >> 8], 1);
    atomicAdd(&hh[dd.y >> 8], 1);
    atomicAdd(&hh[dd.z >> 8], 1);
    atomicAdd(&hh[dd.w >> 8], 1);
  }
  __syncthreads();
  // reserve: one contiguous run per bucket; half 0 then half 1 inside it
  if (tid < 256) {
    int c0 = h0[tid], c1 = h1_[tid], tot = c0 + c1;
    int ofs = (tot > 0) ? atomicAdd(&cursor[tid], tot) : 0;
    cur0[tid] = (tid << CSH) + ofs;
    cur1[tid] = (tid << CSH) + ofs + c0;
  }
  __syncthreads();
  int* cc = half ? cur1 : cur0;
  // pass 2: scatter straight from registers
#pragma unroll
  for (int it = 0; it < 2; ++it) {
    if (val[it]) {
      int p0 = atomicAdd(&cc[d4[it].x >> 8], 1);
      bufA[p0] = make_int2(__float_as_int(w4[it].x),
                           (int)(((unsigned)s4[it].x << 16) | (unsigned)d4[it].x));
      int p1 = atomicAdd(&cc[d4[it].y >> 8], 1);
      bufA[p1] = make_int2(__float_as_int(w4[it].y),
                           (int)(((unsigned)s4[it].y << 16) | (unsigned)d4[it].y));
      int p2 = atomicAdd(&cc[d4[it].z >> 8], 1);
      bufA[p2] = make_int2(__float_as_int(w4[it].z),
                           (int)(((unsigned)s4[it].z << 16) | (unsigned)d4[it].z));
      int p3 = atomicAdd(&cc[d4[it].w >> 8], 1);
      bufA[p3] = make_int2(__float_as_int(w4[it].w),
                           (int)(((unsigned)s4[it].w << 16) | (unsigned)d4[it].w));
    }
  }
  // residual scatter (dead for E=1.6M)
  for (int e = e0 + 4096 + 4 * tid; e < e1; e += 2048) {
    int4 ss = *reinterpret_cast<const int4*>(&src[e]);
    int4 dd = *reinterpret_cast<const int4*>(&dst[e]);
    float4 ww = *reinterpret_cast<const float4*>(&ew[e]);
    int p0 = atomicAdd(&cc[dd.x >> 8], 1);
    bufA[p0] = make_int2(__float_as_int(ww.x), (int)(((unsigned)ss.x << 16) | (unsigned)dd.x));
    int p1 = atomicAdd(&cc[dd.y >> 8], 1);
    bufA[p1] = make_int2(__float_as_int(ww.y), (int)(((unsigned)ss.y << 16) | (unsigned)dd.y));
    int p2 = atomicAdd(&cc[dd.z >> 8], 1);
    bufA[p2] = make_int2(__float_as_int(ww.z), (int)(((unsigned)ss.z << 16) | (unsigned)dd.z));
    int p3 = atomicAdd(&cc[dd.w >> 8], 1);
    bufA[p3] = make_int2(__float_as_int(ww.w), (int)(((unsigned)ss.w << 16) | (unsigned)dd.w));
  }
}

// ============ K2: one block per coarse bucket -> dst-grouped + offs/cnt + dinv ============
// 1024 threads/block (grid pinned at NBC=196 -> latency-bound, maximize waves).
// Records cached in registers across the two phases: bufA read ONCE.
// Output record = (w_bits, src); norm factored (w*dinv[src] in agg, *dinv[dst] once).

__global__ __launch_bounds__(1024) void k_passB(const int2* __restrict__ bufA,
                                                const int* __restrict__ cursor,
                                                int2* __restrict__ bufB,
                                                int* __restrict__ offs,
                                                int* __restrict__ cnt,
                                                float* __restrict__ dinv,
                                                int NBC, int N) {
  int bin = blockIdx.x, tid = threadIdx.x;
  __shared__ int h2[256];
  __shared__ int cur[256];
  __shared__ float dg[256];
  int bbase = bin << CSH;
  int m = cursor[bin];
  if (tid < 256) { h2[tid] = 0; dg[tid] = 0.f; }
  __syncthreads();
  // phase 1: fine histogram of dst&255, records cached in registers
  int2 rloc[16];                 // CAP/1024 = 16 max records per thread
#pragma unroll
  for (int k = 0; k < 16; ++k) {
    int i = tid + k * 1024;
    if (i < m) {
      rloc[k] = bufA[bbase + i];
      atomicAdd(&h2[(unsigned)rloc[k].y & 255u], 1);
    }
  }
  __syncthreads();
  int own = (tid < 256) ? h2[tid] : 0;
  // inclusive Hillis-Steele scan over 256 bins
  for (int o = 1; o < 256; o <<= 1) {
    int u = 0;
    if (tid < 256 && tid >= o) u = h2[tid - o];
    __syncthreads();
    if (tid < 256) h2[tid] += u;
    __syncthreads();
  }
  int nd = (bin << 8) + tid;
  if (tid < 256) {
    int excl = h2[tid] - own;
    cur[tid] = excl;
    if (nd < N) { offs[nd] = bbase + excl; cnt[nd] = own; }
  }
  __syncthreads();
  // phase 2: scatter into dst-grouped order as (w, src) + weighted degree
#pragma unroll
  for (int k = 0; k < 16; ++k) {
    int i = tid + k * 1024;
    if (i < m) {
      int2 r = rloc[k];
      unsigned sd = (unsigned)r.y;
      int dl = (int)(sd & 255u);
      int p = atomicAdd(&cur[dl], 1);
      bufB[bbase + p] = make_int2(r.x, (int)(sd >> 16));
      atomicAdd(&dg[dl], __int_as_float(r.x));
    }
  }
  __syncthreads();
  if (tid < 256 && nd < N) dinv[nd] = rsqrtf(1.0f + dg[tid]);  // self-loop w=1; deg>=1
}

// ============ agg core: 8-lane group per node, shfl-shared records, pipelined ====
// Per 8 edges: one 64B record wave-load + one dinv gather, PREFETCHED one
// iteration ahead so the 2-hop dependent-load chain (recs -> dinv) overlaps the
// previous iteration's 8 h-gathers + FMAs. a/b dual accumulators for FMA ILP.

__device__ __forceinline__ void bfma8(const uint4& v, float w, float* a) {
  a[0] = fmaf(__uint_as_float(v.x << 16), w, a[0]);
  a[1] = fmaf(__uint_as_float(v.x & 0xffff0000u), w, a[1]);
  a[2] = fmaf(__uint_as_float(v.y << 16), w, a[2]);
  a[3] = fmaf(__uint_as_float(v.y & 0xffff0000u), w, a[3]);
  a[4] = fmaf(__uint_as_float(v.z << 16), w, a[4]);
  a[5] = fmaf(__uint_as_float(v.z & 0xffff0000u), w, a[5]);
  a[6] = fmaf(__uint_as_float(v.w << 16), w, a[6]);
  a[7] = fmaf(__uint_as_float(v.w & 0xffff0000u), w, a[7]);
}

// accumulates di*(sum_e w*dinv[s]*h[s] + di*h[node]) into r[8] (pre-bias)
__device__ __forceinline__ void agg_node(const u16* __restrict__ h,
                                         const int2* __restrict__ recs,
                                         const float* __restrict__ dinv,
                                         int beg, int end, int node, float di,
                                         int lane, int p8, float* r) {
  float a[8], b[8];
  {
    uint4 v = *reinterpret_cast<const uint4*>(&h[(size_t)node * HID + p8]);
    a[0] = __uint_as_float(v.x << 16) * di;          // self: di*(di*h) after epilogue
    a[1] = __uint_as_float(v.x & 0xffff0000u) * di;
    a[2] = __uint_as_float(v.y << 16) * di;
    a[3] = __uint_as_float(v.y & 0xffff0000u) * di;
    a[4] = __uint_as_float(v.z << 16) * di;
    a[5] = __uint_as_float(v.z & 0xffff0000u) * di;
    a[6] = __uint_as_float(v.w << 16) * di;
    a[7] = __uint_as_float(v.w & 0xffff0000u) * di;
#pragma unroll
    for (int j = 0; j < 8; ++j) b[j] = 0.f;
  }

  const int gb = lane & 56;           // group base lane
  const int l7 = lane & 7;
  int i = beg;
  if (i + 8 <= end) {
    ull rr = *reinterpret_cast<const ull*>(&recs[i + l7]);
    float dv = dinv[(int)(rr >> 32)];
    for (;;) {
      float wd = __uint_as_float((unsigned)rr) * dv;
      ull ru = (rr & 0xffffffff00000000ull) | (ull)__float_as_uint(wd);
      bool more = (i + 16 <= end);
      ull rr_n = 0; float dv_n = 0.f;
      if (more) {                     // prefetch next iteration's chain
        rr_n = *reinterpret_cast<const ull*>(&recs[i + 8 + l7]);
        dv_n = dinv[(int)(rr_n >> 32)];
      }
#pragma unroll
      for (int k = 0; k < 8; ++k) {
        ull q = __shfl(ru, gb | k, 64);
        float wk = __uint_as_float((unsigned)q);
        int sk = (int)(q >> 32);
        uint4 vk = *reinterpret_cast<const uint4*>(&h[(size_t)sk * HID + p8]);
        bfma8(vk, wk, (k & 1) ? b : a);
      }
      i += 8;
      if (!more) break;
      rr = rr_n; dv = dv_n;
    }
  }
  if (i + 4 <= end) {
    int2 r0 = recs[i];     int2 r1 = recs[i + 1];
    int2 r2 = recs[i + 2]; int2 r3 = recs[i + 3];
    uint4 v0 = *reinterpret_cast<const uint4*>(&h[(size_t)r0.y * HID + p8]);
    uint4 v1 = *reinterpret_cast<const uint4*>(&h[(size_t)r1.y * HID + p8]);
    uint4 v2 = *reinterpret_cast<const uint4*>(&h[(size_t)r2.y * HID + p8]);
    uint4 v3 = *reinterpret_cast<const uint4*>(&h[(size_t)r3.y * HID + p8]);
    bfma8(v0, __int_as_float(r0.x) * dinv[r0.y], a);
    bfma8(v1, __int_as_float(r1.x) * dinv[r1.y], b);
    bfma8(v2, __int_as_float(r2.x) * dinv[r2.y], a);
    bfma8(v3, __int_as_float(r3.x) * dinv[r3.y], b);
    i += 4;
  }
  if (i + 2 <= end) {
    int2 r0 = recs[i];     int2 r1 = recs[i + 1];
    uint4 v0 = *reinterpret_cast<const uint4*>(&h[(size_t)r0.y * HID + p8]);
    uint4 v1 = *reinterpret_cast<const uint4*>(&h[(size_t)r1.y * HID + p8]);
    bfma8(v0, __int_as_float(r0.x) * dinv[r0.y], a);
    bfma8(v1, __int_as_float(r1.x) * dinv[r1.y], b);
    i += 2;
  }
  if (i < end) {
    int2 r0 = recs[i];
    uint4 v0 = *reinterpret_cast<const uint4*>(&h[(size_t)r0.y * HID + p8]);
    bfma8(v0, __int_as_float(r0.x) * dinv[r0.y], a);
  }
#pragma unroll
  for (int j = 0; j < 8; ++j) r[j] = (a[j] + b[j]) * di;   // apply dinv[dst] once
}

// ============ K3: fused agg1 + gemm2 — 256 threads / 32 nodes ============
// Smaller blocks (round-8 win: occ 39%->higher, straggler granularity halved).
// Phase A: 4 waves aggregate h1 = relu(conv1+b1) -> h1 (global, resid) + XT (LDS).
// Phase B: 32x64 gemm2 from LDS. h2 separate buffer (in-place h would race).

__global__ __launch_bounds__(256) void k_agg_gemm(const u16* __restrict__ h,
                                                  const int2* __restrict__ recs,
                                                  const int* __restrict__ offs,
                                                  const int* __restrict__ cnt,
                                                  const float* __restrict__ dinv,
                                                  const float* __restrict__ bias,
                                                  const float* __restrict__ W2,
                                                  float* __restrict__ h1,
                                                  u16* __restrict__ h2,
                                                  int n_nodes) {
  __shared__ float S[(32 + 64) * PAD];
  float* XT = S;
  float* WL = S + 32 * PAD;
  int tid = threadIdx.x;
  int lane = tid & 63;
  int p8 = (lane & 7) * 8;
  int nl = (tid >> 6) * 8 + (lane >> 3);        // 0..31 local node
  int node = blockIdx.x * 32 + nl;
  if (node < n_nodes) {
    float di = dinv[node];
    float r[8];
    agg_node(h, recs, dinv, offs[node], offs[node] + cnt[node], node, di,
             lane, p8, r);
    float4 bb0 = *reinterpret_cast<const float4*>(&bias[p8]);
    float4 bb1 = *reinterpret_cast<const float4*>(&bias[p8 + 4]);
    r[0] += bb0.x; r[1] += bb0.y; r[2] += bb0.z; r[3] += bb0.w;
    r[4] += bb1.x; r[5] += bb1.y; r[6] += bb1.z; r[7] += bb1.w;
#pragma unroll
    for (int j = 0; j < 8; ++j) r[j] = fmaxf(r[j], 0.f);
    float4 lo = make_float4(r[0], r[1], r[2], r[3]);
    float4 hi = make_float4(r[4], r[5], r[6], r[7]);
    *reinterpret_cast<float4*>(&h1[(size_t)node * HID + p8]) = lo;
    *reinterpret_cast<float4*>(&h1[(size_t)node * HID + p8 + 4]) = hi;
    *reinterpret_cast<float4*>(&XT[nl * PAD + p8]) = lo;
    *reinterpret_cast<float4*>(&XT[nl * PAD + p8 + 4]) = hi;
  }
  // Phase B (all threads; gemm_tile starts with __syncthreads covering XT writes)
  gemm_tile<HID, 256, true>(nullptr, W2, h2, XT, WL, blockIdx.x * 32, n_nodes, tid);
}

// ============ K4: final aggregation (layer 2) ============
// out = di*(sum w*dinv[s]*h2[s] + di*h2[node]) + b2 + h1

__global__ __launch_bounds__(256) void k_agg2(const u16* __restrict__ h,
                                              const int2* __restrict__ recs,
                                              const int* __restrict__ offs,
                                              const int* __restrict__ cnt,
                                              const float* __restrict__ dinv,
                                              const float* __restrict__ bias,
                                              const float* __restrict__ resid,
                                              float* __restrict__ out, int n_nodes) {
  int tid = threadIdx.x;
  int lane = tid & 63;
  int p8 = (lane & 7) * 8;
  int node = (blockIdx.x * 4 + (tid >> 6)) * 8 + (lane >> 3);   // 32 nodes/block
  if (node >= n_nodes) return;
  float di = dinv[node];
  float r[8];
  agg_node(h, recs, dinv, offs[node], offs[node] + cnt[node], node, di,
           lane, p8, r);
  float4 bb0 = *reinterpret_cast<const float4*>(&bias[p8]);
  float4 bb1 = *reinterpret_cast<const float4*>(&bias[p8 + 4]);
  float4 rs0 = *reinterpret_cast<const float4*>(&resid[(size_t)node * HID + p8]);
  float4 rs1 = *reinterpret_cast<const float4*>(&resid[(size_t)node * HID + p8 + 4]);
  r[0] += bb0.x + rs0.x; r[1] += bb0.y + rs0.y;
  r[2] += bb0.z + rs0.z; r[3] += bb0.w + rs0.w;
  r[4] += bb1.x + rs1.x; r[5] += bb1.y + rs1.y;
  r[6] += bb1.z + rs1.z; r[7] += bb1.w + rs1.w;
  *reinterpret_cast<float4*>(&out[(size_t)node * HID + p8]) =
      make_float4(r[0], r[1], r[2], r[3]);
  *reinterpret_cast<float4*>(&out[(size_t)node * HID + p8 + 4]) =
      make_float4(r[4], r[5], r[6], r[7]);
}

// ============ launcher ============

extern "C" void kernel_launch(void* const* d_in, const int* in_sizes, int n_in,
                              void* d_out, int out_size, void* d_ws, size_t ws_size,
                              hipStream_t stream) {
  const float* x  = (const float*)d_in[0];
  const int*   ei = (const int*)d_in[1];
  const float* ew = (const float*)d_in[2];
  const float* W1 = (const float*)d_in[3];
  const float* b1 = (const float*)d_in[4];
  const float* W2 = (const float*)d_in[5];
  const float* b2 = (const float*)d_in[6];
  float* out = (float*)d_out;

  const int N = in_sizes[0] / DIN;
  const int E = in_sizes[2];
  const int* src = ei;        // ei shape (2,E) row-major
  const int* dst = ei + E;

  const int NBC = (N + 255) >> 8;          // coarse buckets (196 for N=50000)
  const int chunk = (((E + NBLK - 1) / NBLK) + 3) & ~3;   // multiple of 4 -> int4 loads
  const int nslab = NBC << CSH;            // total slab entries

  char* p = (char*)d_ws;
  auto carve = [&](size_t bytes) {
    char* r = p;
    p += (bytes + 255) & ~(size_t)255;
    return r;
  };
  int*   cursor = (int*)carve(256 * 4);
  int*   offs   = (int*)carve((size_t)N * 4);
  int*   cnt    = (int*)carve((size_t)N * 4);
  float* dinv   = (float*)carve((size_t)N * 4);
  int2*  bufA   = (int2*)carve((size_t)nslab * 8);
  int2*  bufB   = (int2*)carve((size_t)nslab * 8);
  u16*   h      = (u16*)carve((size_t)N * HID * 2);   // bf16 gemm1 output
  u16*   h2     = (u16*)carve((size_t)N * HID * 2);   // bf16 gemm2 output
  float* h1     = (float*)carve((size_t)N * HID * 4); // fp32 layer-1 activations

  int gblk  = (N + 63) / 64;                  // 64-node gemm1 tiles (782)
  int gblk2 = (N + 31) / 32;                  // 32-node agg_gemm blocks (1563)
  int ablk  = (N + 31) / 32;                  // 32 nodes per 256-thread block

  // ---- K1: build (edges) + gemm1 (independent) in one launch ----
  hipMemsetAsync(cursor, 0, 256 * 4, stream);
  k_build_gemm<<<NBLK + gblk, 512, 0, stream>>>(src, dst, ew, cursor, bufA, E, chunk,
                                                x, W1, h, N);
  // ---- K2: bucket sort -> dst-grouped records + dinv ----
  k_passB<<<NBC, 1024, 0, stream>>>(bufA, cursor, bufB, offs, cnt, dinv, NBC, N);
  // ---- K3: agg1 (+bias,relu) fused with gemm2 ----
  k_agg_gemm<<<gblk2, 256, 0, stream>>>(h, bufB, offs, cnt, dinv, b1, W2, h1, h2, N);
  // ---- K4: agg2 + bias + resid -> out ----
  k_agg2<<<ablk, 256, 0, stream>>>(h2, bufB, offs, cnt, dinv, b2, h1, out, N);
}